// Round 4
// baseline (1163.995 us; speedup 1.0000x reference)
//
#include <hip/hip_runtime.h>
#include <hip/hip_bf16.h>
#include <stdint.h>

#define SEQ   2048
#define DM    512
#define NH    8
#define DH    64
#define BHN   32        // B*H
#define MR    8192      // B*SEQ
#define NITER 10
#define SCALE_LOG2E 0.18033688011112042f   // (1/8) * log2(e)
#define BETA  0.5f

typedef unsigned short u16;
typedef unsigned char  u8;
typedef long i64;  // 64-bit on amdgcn
typedef __attribute__((ext_vector_type(8))) short bf16x8;
typedef __attribute__((ext_vector_type(4))) float f32x4;
typedef __attribute__((ext_vector_type(4))) int i32x4;

__device__ __forceinline__ u16 f2bf(float f) {
  union { float f; uint32_t u; } v; v.f = f;
  uint32_t r = v.u + 0x7FFFu + ((v.u >> 16) & 1u);
  return (u16)(r >> 16);
}
__device__ __forceinline__ float bf2f(u16 h) {
  union { uint32_t u; float f; } v; v.u = ((uint32_t)h) << 16;
  return v.f;
}
__device__ __forceinline__ void g2l16(const void* g, void* l) {
  __builtin_amdgcn_global_load_lds(
      (const __attribute__((address_space(1))) void*)g,
      (__attribute__((address_space(3))) void*)l, 16, 0, 0);
}
__device__ __forceinline__ uint32_t pk4_fp8(float a, float b, float c, float d) {
  int w = 0;
  w = __builtin_amdgcn_cvt_pk_fp8_f32(a, b, w, false);  // bytes 0,1
  w = __builtin_amdgcn_cvt_pk_fp8_f32(c, d, w, true);   // bytes 2,3
  return (uint32_t)w;
}
__device__ __forceinline__ u8 f2fp8(float a) {
  return (u8)(__builtin_amdgcn_cvt_pk_fp8_f32(a, a, 0, false) & 0xFF);
}

// ---------------- diagnostic: fill out with 1e6 (ws too small) ----------------
__global__ __launch_bounds__(256) void k_diag(float* __restrict__ out, int n) {
  int i = blockIdx.x * 256 + threadIdx.x;
  if (i < n) out[i] = 1.0e6f;
}

// ---------------- fp32 -> bf16 bulk convert (n4 = n/4) ----------------
__global__ __launch_bounds__(256) void k_cvt(const float* __restrict__ s,
                                             u16* __restrict__ d, int n4) {
  int i = blockIdx.x * 256 + threadIdx.x;
  if (i >= n4) return;
  float4 v = reinterpret_cast<const float4*>(s)[i];
  short4 o;
  o.x = (short)f2bf(v.x); o.y = (short)f2bf(v.y);
  o.z = (short)f2bf(v.z); o.w = (short)f2bf(v.w);
  reinterpret_cast<short4*>(d)[i] = o;
}

// ---------------- generic 128x128x32 bf16 GEMM, C = A * B^T ----------------
// MODE 0: out = bf16 [b][h][s][d]            (Q/K projection)
// MODE 1: out = bf16 [bh][d][s], out2 = fp8   (V projection, transposed)
// MODE 2: out = fp32 [m][n] + bias            (output projection)
template <int MODE>
__global__ __launch_bounds__(256, 2) void k_gemm_bt(
    const u16* __restrict__ A, const u16* __restrict__ Bt,
    void* __restrict__ out, void* __restrict__ out2,
    const float* __restrict__ bias, int K, int lda, int ldb, int N) {
  __shared__ __align__(16) u16 lsA[4][128][8];
  __shared__ __align__(16) u16 lsB[4][128][8];
  const int t = threadIdx.x;
  const int mbase = blockIdx.y * 128, nbase = blockIdx.x * 128;
  const int w = t >> 6, l = t & 63;
  const int wr = w >> 1, wc = w & 1;
  const int lr = l & 15, lg = l >> 4;
  f32x4 acc[4][4] = {};
  for (int k0 = 0; k0 < K; k0 += 32) {
#pragma unroll
    for (int i = 0; i < 2; ++i) {
      int idx = t + i * 256;
      int c = idx >> 7, row = idx & 127;
      g2l16(A  + (size_t)(mbase + row) * lda + k0 + c * 8, &lsA[c][row][0]);
      g2l16(Bt + (size_t)(nbase + row) * ldb + k0 + c * 8, &lsB[c][row][0]);
    }
    __syncthreads();
    bf16x8 af[4], bg[4];
#pragma unroll
    for (int f = 0; f < 4; ++f) {
      af[f] = *reinterpret_cast<const bf16x8*>(&lsA[lg][wr * 64 + f * 16 + lr][0]);
      bg[f] = *reinterpret_cast<const bf16x8*>(&lsB[lg][wc * 64 + f * 16 + lr][0]);
    }
#pragma unroll
    for (int mf = 0; mf < 4; ++mf)
#pragma unroll
      for (int nf = 0; nf < 4; ++nf)
        acc[mf][nf] = __builtin_amdgcn_mfma_f32_16x16x32_bf16(af[mf], bg[nf], acc[mf][nf], 0, 0, 0);
    __syncthreads();
  }
#pragma unroll
  for (int mf = 0; mf < 4; ++mf) {
#pragma unroll
    for (int nf = 0; nf < 4; ++nf) {
      const int m0 = mbase + wr * 64 + mf * 16 + lg * 4;
      const int n  = nbase + wc * 64 + nf * 16 + lr;
      if (MODE == 0) {
        int h = n >> 6, d = n & 63;
#pragma unroll
        for (int j = 0; j < 4; ++j) {
          int m = m0 + j, b = m >> 11, s = m & 2047;
          ((u16*)out)[((((size_t)b * NH + h) * SEQ + s) << 6) + d] = f2bf(acc[mf][nf][j]);
        }
      } else if (MODE == 1) {
        int h = n >> 6, d = n & 63;
        int b = m0 >> 11, s0 = m0 & 2047;
        size_t base = (((size_t)b * NH + h) * DH + d) * SEQ + s0;
        short4 pk;
        pk.x = (short)f2bf(acc[mf][nf][0]); pk.y = (short)f2bf(acc[mf][nf][1]);
        pk.z = (short)f2bf(acc[mf][nf][2]); pk.w = (short)f2bf(acc[mf][nf][3]);
        *reinterpret_cast<short4*>(&((u16*)out)[base]) = pk;
        *reinterpret_cast<uint32_t*>(&((u8*)out2)[base]) =
            pk4_fp8(acc[mf][nf][0], acc[mf][nf][1], acc[mf][nf][2], acc[mf][nf][3]);
      } else {
        float bv = bias[n];
#pragma unroll
        for (int j = 0; j < 4; ++j)
          ((float*)out)[(size_t)(m0 + j) * N + n] = acc[mf][nf][j] + bv;
      }
    }
  }
}

// ------- per-head scores: E(fp8) = exp(scale * Q K^T), Dsum += rowsums -------
// Epilogue: fp8 tile bounced through LDS, stored with coalesced dwordx4.
__global__ __launch_bounds__(256, 2) void k_scores(
    const u16* __restrict__ Q, const u16* __restrict__ Kh,
    u8* __restrict__ E, float* __restrict__ Dsum) {
  __shared__ __align__(16) u16 lsA[4][128][8];
  __shared__ __align__(16) u16 lsB[4][128][8];
  __shared__ __align__(16) u8 stile[128 * 144];   // 144-byte row pitch (16B aligned)
  const int t = threadIdx.x;
  const int head = blockIdx.z;
  const int mbase = blockIdx.y * 128, nbase = blockIdx.x * 128;
  const int w = t >> 6, l = t & 63;
  const int wr = w >> 1, wc = w & 1;
  const int lr = l & 15, lg = l >> 4;
  const u16* Aq = Q  + (size_t)head * SEQ * DH;
  const u16* Bk = Kh + (size_t)head * SEQ * DH;
  f32x4 acc[4][4] = {};
  for (int k0 = 0; k0 < DH; k0 += 32) {
#pragma unroll
    for (int i = 0; i < 2; ++i) {
      int idx = t + i * 256;
      int c = idx >> 7, row = idx & 127;
      g2l16(Aq + (size_t)(mbase + row) * DH + k0 + c * 8, &lsA[c][row][0]);
      g2l16(Bk + (size_t)(nbase + row) * DH + k0 + c * 8, &lsB[c][row][0]);
    }
    __syncthreads();
    bf16x8 af[4], bg[4];
#pragma unroll
    for (int f = 0; f < 4; ++f) {
      af[f] = *reinterpret_cast<const bf16x8*>(&lsA[lg][wr * 64 + f * 16 + lr][0]);
      bg[f] = *reinterpret_cast<const bf16x8*>(&lsB[lg][wc * 64 + f * 16 + lr][0]);
    }
#pragma unroll
    for (int mf = 0; mf < 4; ++mf)
#pragma unroll
      for (int nf = 0; nf < 4; ++nf)
        acc[mf][nf] = __builtin_amdgcn_mfma_f32_16x16x32_bf16(af[mf], bg[nf], acc[mf][nf], 0, 0, 0);
    __syncthreads();
  }
  // exp + rowsums + fp8 into LDS tile
  float rs[4][4];
#pragma unroll
  for (int mf = 0; mf < 4; ++mf)
#pragma unroll
    for (int j = 0; j < 4; ++j) rs[mf][j] = 0.f;
#pragma unroll
  for (int mf = 0; mf < 4; ++mf) {
#pragma unroll
    for (int nf = 0; nf < 4; ++nf) {
      const int r0 = wr * 64 + mf * 16 + lg * 4;
      const int c  = wc * 64 + nf * 16 + lr;
#pragma unroll
      for (int j = 0; j < 4; ++j) {
        float e = exp2f(acc[mf][nf][j] * SCALE_LOG2E);
        stile[(r0 + j) * 144 + c] = f2fp8(e);
        rs[mf][j] += e;
      }
    }
  }
#pragma unroll
  for (int mask = 1; mask <= 8; mask <<= 1)
#pragma unroll
    for (int mf = 0; mf < 4; ++mf)
#pragma unroll
      for (int j = 0; j < 4; ++j) rs[mf][j] += __shfl_xor(rs[mf][j], mask, 64);
  if (lr == 0) {
#pragma unroll
    for (int mf = 0; mf < 4; ++mf)
#pragma unroll
      for (int j = 0; j < 4; ++j)
        atomicAdd(&Dsum[head * SEQ + mbase + wr * 64 + mf * 16 + lg * 4 + j], rs[mf][j]);
  }
  __syncthreads();
  // coalesced store: 8 threads cover one 128B row segment
  u8* Eh = E + (size_t)head * SEQ * SEQ;
#pragma unroll
  for (int p = 0; p < 4; ++p) {
    int row = p * 32 + (t >> 3), c16 = t & 7;
    i32x4 v = *reinterpret_cast<const i32x4*>(&stile[row * 144 + c16 * 16]);
    *reinterpret_cast<i32x4*>(&Eh[(size_t)(mbase + row) * SEQ + nbase + c16 * 16]) = v;
  }
}

// ---------------- Fac = beta / Dsum ----------------
__global__ __launch_bounds__(256) void k_fac(const float* __restrict__ Dsum,
                                             float* __restrict__ Fac, int n) {
  int i = blockIdx.x * 256 + threadIdx.x;
  if (i < n) Fac[i] = BETA / Dsum[i];
}

// ------ Horner step (fp8, barrier-free streaming): r_out = V + Fac[m]*(E@r_in)
// E: [bh][s][s] fp8; rin8/rout8: [bh][d=64][s] fp8; VT: [bh][d][s] bf16
// A-frags stream from global (L3); B-frags stream from global (L1/L2-resident,
// 128 KB/head). Software-pipelined 4 deep, no LDS, no barriers.
__global__ __launch_bounds__(256, 2) void k_horner8(
    const u8* __restrict__ E, const u8* __restrict__ rin8,
    const u16* __restrict__ VT, const float* __restrict__ Fac,
    u8* __restrict__ rout8, u16* __restrict__ attn, int writeAttn) {
  const int t = threadIdx.x;
  const int head = blockIdx.y;
  const int mbase = blockIdx.x * 128;
  const int w = t >> 6, l = t & 63;
  const int lr = l & 15, lg = l >> 4;
  const u8* Eh = E + (size_t)head * SEQ * SEQ;
  const u8* Rh = rin8 + (size_t)head * DH * SEQ;
  const int kl = lg * 8;
  const u8* pa0 = Eh + (size_t)(mbase + w * 32 + lr) * SEQ + kl;
  const u8* pa1 = pa0 + (size_t)16 * SEQ;
  const u8* pb0 = Rh + (size_t)(lr)      * SEQ + kl;
  const u8* pb1 = Rh + (size_t)(16 + lr) * SEQ + kl;
  const u8* pb2 = Rh + (size_t)(32 + lr) * SEQ + kl;
  const u8* pb3 = Rh + (size_t)(48 + lr) * SEQ + kl;
  f32x4 acc[2][4] = {};
  i64 fa0[4], fa1[4], fb0[4], fb1[4], fb2[4], fb3[4];
#pragma unroll
  for (int p = 0; p < 4; ++p) {
    fa0[p] = *(const i64*)(pa0 + p * 32);
    fa1[p] = *(const i64*)(pa1 + p * 32);
    fb0[p] = *(const i64*)(pb0 + p * 32);
    fb1[p] = *(const i64*)(pb1 + p * 32);
    fb2[p] = *(const i64*)(pb2 + p * 32);
    fb3[p] = *(const i64*)(pb3 + p * 32);
  }
  for (int g = 0; g < 15; ++g) {
#pragma unroll
    for (int u = 0; u < 4; ++u) {
      const int k0 = (g * 4 + u) * 32;
      acc[0][0] = __builtin_amdgcn_mfma_f32_16x16x32_fp8_fp8(fa0[u], fb0[u], acc[0][0], 0, 0, 0);
      acc[1][0] = __builtin_amdgcn_mfma_f32_16x16x32_fp8_fp8(fa1[u], fb0[u], acc[1][0], 0, 0, 0);
      acc[0][1] = __builtin_amdgcn_mfma_f32_16x16x32_fp8_fp8(fa0[u], fb1[u], acc[0][1], 0, 0, 0);
      acc[1][1] = __builtin_amdgcn_mfma_f32_16x16x32_fp8_fp8(fa1[u], fb1[u], acc[1][1], 0, 0, 0);
      acc[0][2] = __builtin_amdgcn_mfma_f32_16x16x32_fp8_fp8(fa0[u], fb2[u], acc[0][2], 0, 0, 0);
      acc[1][2] = __builtin_amdgcn_mfma_f32_16x16x32_fp8_fp8(fa1[u], fb2[u], acc[1][2], 0, 0, 0);
      acc[0][3] = __builtin_amdgcn_mfma_f32_16x16x32_fp8_fp8(fa0[u], fb3[u], acc[0][3], 0, 0, 0);
      acc[1][3] = __builtin_amdgcn_mfma_f32_16x16x32_fp8_fp8(fa1[u], fb3[u], acc[1][3], 0, 0, 0);
      fa0[u] = *(const i64*)(pa0 + k0 + 128);
      fa1[u] = *(const i64*)(pa1 + k0 + 128);
      fb0[u] = *(const i64*)(pb0 + k0 + 128);
      fb1[u] = *(const i64*)(pb1 + k0 + 128);
      fb2[u] = *(const i64*)(pb2 + k0 + 128);
      fb3[u] = *(const i64*)(pb3 + k0 + 128);
    }
  }
#pragma unroll
  for (int u = 0; u < 4; ++u) {
    acc[0][0] = __builtin_amdgcn_mfma_f32_16x16x32_fp8_fp8(fa0[u], fb0[u], acc[0][0], 0, 0, 0);
    acc[1][0] = __builtin_amdgcn_mfma_f32_16x16x32_fp8_fp8(fa1[u], fb0[u], acc[1][0], 0, 0, 0);
    acc[0][1] = __builtin_amdgcn_mfma_f32_16x16x32_fp8_fp8(fa0[u], fb1[u], acc[0][1], 0, 0, 0);
    acc[1][1] = __builtin_amdgcn_mfma_f32_16x16x32_fp8_fp8(fa1[u], fb1[u], acc[1][1], 0, 0, 0);
    acc[0][2] = __builtin_amdgcn_mfma_f32_16x16x32_fp8_fp8(fa0[u], fb2[u], acc[0][2], 0, 0, 0);
    acc[1][2] = __builtin_amdgcn_mfma_f32_16x16x32_fp8_fp8(fa1[u], fb2[u], acc[1][2], 0, 0, 0);
    acc[0][3] = __builtin_amdgcn_mfma_f32_16x16x32_fp8_fp8(fa0[u], fb3[u], acc[0][3], 0, 0, 0);
    acc[1][3] = __builtin_amdgcn_mfma_f32_16x16x32_fp8_fp8(fa1[u], fb3[u], acc[1][3], 0, 0, 0);
  }
  const u16* VTh = VT + (size_t)head * DH * SEQ;
  const float* Fh = Fac + head * SEQ;
  u8* Ro8 = rout8 + (size_t)head * DH * SEQ;
  const int b = head >> 3, hh = head & 7;
#pragma unroll
  for (int mf = 0; mf < 2; ++mf) {
#pragma unroll
    for (int nf = 0; nf < 4; ++nf) {
      const int m0 = mbase + w * 32 + mf * 16 + lg * 4;
      const int n  = nf * 16 + lr;
      short4 vv = *reinterpret_cast<const short4*>(&VTh[(size_t)n * SEQ + m0]);
      float4 fc = *reinterpret_cast<const float4*>(&Fh[m0]);
      float o0 = bf2f((u16)vv.x) + fc.x * acc[mf][nf][0];
      float o1 = bf2f((u16)vv.y) + fc.y * acc[mf][nf][1];
      float o2 = bf2f((u16)vv.z) + fc.z * acc[mf][nf][2];
      float o3 = bf2f((u16)vv.w) + fc.w * acc[mf][nf][3];
      *reinterpret_cast<uint32_t*>(&Ro8[(size_t)n * SEQ + m0]) = pk4_fp8(o0, o1, o2, o3);
      if (writeAttn) {
        size_t base = ((size_t)b * SEQ + m0) * DM + hh * DH + n;
        attn[base]          = f2bf(o0);
        attn[base + DM]     = f2bf(o1);
        attn[base + 2 * DM] = f2bf(o2);
        attn[base + 3 * DM] = f2bf(o3);
      }
    }
  }
}

extern "C" void kernel_launch(void* const* d_in, const int* in_sizes, int n_in,
                              void* d_out, int out_size, void* d_ws, size_t ws_size,
                              hipStream_t stream) {
  const float* q_f = (const float*)d_in[0];
  const float* k_f = (const float*)d_in[1];
  const float* v_f = (const float*)d_in[2];
  const float* Wq  = (const float*)d_in[3];
  const float* Wk  = (const float*)d_in[4];
  const float* Wv  = (const float*)d_in[5];
  const float* Wo  = (const float*)d_in[6];
  const float* bo  = (const float*)d_in[7];

  char* ws = (char*)d_ws;
  size_t o = 0;
  auto take = [&](size_t b) { size_t p = o; o += (b + 255) & ~(size_t)255; return p; };
  const size_t SZ_ACT = (size_t)MR * DM * 2;        // 8 MB
  const size_t SZ_W   = (size_t)DM * DM * 2;        // 0.5 MB
  const size_t SZ_R8  = (size_t)BHN * DH * SEQ;     // 4 MB
  size_t o_qbf = take(SZ_ACT);                      // later: attn
  size_t o_kbf = take(SZ_ACT);                      // later: r8A + r8B
  size_t o_vbf = take(SZ_ACT);
  size_t o_wq = take(SZ_W), o_wk = take(SZ_W), o_wv = take(SZ_W), o_wo = take(SZ_W);
  size_t o_Qh = take(SZ_ACT);
  size_t o_Kh = take(SZ_ACT);
  size_t o_VT = take(SZ_ACT);
  size_t o_V8 = take(SZ_R8);
  size_t o_Ds = take((size_t)BHN * SEQ * 4);
  size_t o_Fc = take((size_t)BHN * SEQ * 4);
  size_t o_E  = take((size_t)BHN * SEQ * SEQ);      // 128 MB fp8
  if (ws_size < o) {  // workspace insufficient -> unambiguous diagnostic
    k_diag<<<dim3((out_size + 255) / 256), dim3(256), 0, stream>>>((float*)d_out, out_size);
    return;
  }
  u16* q_bf = (u16*)(ws + o_qbf);
  u16* k_bf = (u16*)(ws + o_kbf);
  u16* v_bf = (u16*)(ws + o_vbf);
  u16* wq_bf = (u16*)(ws + o_wq); u16* wk_bf = (u16*)(ws + o_wk);
  u16* wv_bf = (u16*)(ws + o_wv); u16* wo_bf = (u16*)(ws + o_wo);
  u16* Qh = (u16*)(ws + o_Qh);
  u16* Kh = (u16*)(ws + o_Kh);
  u16* VT = (u16*)(ws + o_VT);
  u8*  V8 = (u8*)(ws + o_V8);
  float* Dsum = (float*)(ws + o_Ds);
  float* Fac  = (float*)(ws + o_Fc);
  u8* E = (u8*)(ws + o_E);
  // aliases (lifetimes disjoint): attn over q_bf, r8 ping-pong over k_bf
  u16* attn = (u16*)(ws + o_qbf);
  u8* r8A = (u8*)(ws + o_kbf);
  u8* r8B = (u8*)(ws + o_kbf + SZ_R8);

  // 1) fp32 -> bf16 conversions
  {
    int n4 = MR * DM / 4;
    k_cvt<<<dim3((n4 + 255) / 256), dim3(256), 0, stream>>>(q_f, q_bf, n4);
    k_cvt<<<dim3((n4 + 255) / 256), dim3(256), 0, stream>>>(k_f, k_bf, n4);
    k_cvt<<<dim3((n4 + 255) / 256), dim3(256), 0, stream>>>(v_f, v_bf, n4);
    int w4 = DM * DM / 4;
    k_cvt<<<dim3((w4 + 255) / 256), dim3(256), 0, stream>>>(Wq, wq_bf, w4);
    k_cvt<<<dim3((w4 + 255) / 256), dim3(256), 0, stream>>>(Wk, wk_bf, w4);
    k_cvt<<<dim3((w4 + 255) / 256), dim3(256), 0, stream>>>(Wv, wv_bf, w4);
    k_cvt<<<dim3((w4 + 255) / 256), dim3(256), 0, stream>>>(Wo, wo_bf, w4);
  }

  // 2) projections
  dim3 pgrid(DM / 128, MR / 128);
  k_gemm_bt<0><<<pgrid, dim3(256), 0, stream>>>(q_bf, wq_bf, Qh, nullptr, nullptr, DM, DM, DM, DM);
  k_gemm_bt<0><<<pgrid, dim3(256), 0, stream>>>(k_bf, wk_bf, Kh, nullptr, nullptr, DM, DM, DM, DM);
  k_gemm_bt<1><<<pgrid, dim3(256), 0, stream>>>(v_bf, wv_bf, VT, V8, nullptr, DM, DM, DM, DM);

  // 3) scores: E = exp(scale*QK^T) in fp8, Dsum = fp32 row sums
  hipMemsetAsync(Dsum, 0, (size_t)BHN * SEQ * 4, stream);
  k_scores<<<dim3(SEQ / 128, SEQ / 128, BHN), dim3(256), 0, stream>>>(Qh, Kh, E, Dsum);
  k_fac<<<dim3(BHN * SEQ / 256), dim3(256), 0, stream>>>(Dsum, Fac, BHN * SEQ);

  // 4) Horner: r <- V + (beta/D) * E @ r, 10 times (r0 = V); last writes attn
  const u8* rin8 = V8;
  u8* r8bufs[2] = {r8A, r8B};
  for (int it = 0; it < NITER; ++it) {
    u8* ro8 = r8bufs[it & 1];
    k_horner8<<<dim3(SEQ / 128, BHN), dim3(256), 0, stream>>>(
        E, rin8, VT, Fac, ro8, attn, (it == NITER - 1) ? 1 : 0);
    rin8 = ro8;
  }

  // 5) output projection: out = attn @ Wo^T + bo (fp32)
  k_gemm_bt<2><<<pgrid, dim3(256), 0, stream>>>(attn, wo_bf, d_out, nullptr, bo, DM, DM, DM, DM);
}

// Round 5
// 652.257 us; speedup vs baseline: 1.7846x; 1.7846x over previous
//
#include <hip/hip_runtime.h>
#include <hip/hip_bf16.h>
#include <stdint.h>

#define SEQ   2048
#define DM    512
#define NH    8
#define DH    64
#define BHN   32        // B*H
#define MR    8192      // B*SEQ
#define NITER 10
#define SCALE_LOG2E 0.18033688011112042f   // (1/8) * log2(e)
#define BETA  0.5f

typedef unsigned short u16;
typedef unsigned char  u8;
typedef long i64;  // 64-bit on amdgcn
typedef __attribute__((ext_vector_type(8))) short bf16x8;
typedef __attribute__((ext_vector_type(4))) float f32x4;
typedef __attribute__((ext_vector_type(4))) int i32x4;

__device__ __forceinline__ u16 f2bf(float f) {
  union { float f; uint32_t u; } v; v.f = f;
  uint32_t r = v.u + 0x7FFFu + ((v.u >> 16) & 1u);
  return (u16)(r >> 16);
}
__device__ __forceinline__ float bf2f(u16 h) {
  union { uint32_t u; float f; } v; v.u = ((uint32_t)h) << 16;
  return v.f;
}
__device__ __forceinline__ void g2l16(const void* g, void* l) {
  __builtin_amdgcn_global_load_lds(
      (const __attribute__((address_space(1))) void*)g,
      (__attribute__((address_space(3))) void*)l, 16, 0, 0);
}
__device__ __forceinline__ uint32_t pk4_fp8(float a, float b, float c, float d) {
  int w = 0;
  w = __builtin_amdgcn_cvt_pk_fp8_f32(a, b, w, false);  // bytes 0,1
  w = __builtin_amdgcn_cvt_pk_fp8_f32(c, d, w, true);   // bytes 2,3
  return (uint32_t)w;
}
__device__ __forceinline__ u8 f2fp8(float a) {
  return (u8)(__builtin_amdgcn_cvt_pk_fp8_f32(a, a, 0, false) & 0xFF);
}

// ---------------- diagnostic: fill out with 1e6 (ws too small) ----------------
__global__ __launch_bounds__(256) void k_diag(float* __restrict__ out, int n) {
  int i = blockIdx.x * 256 + threadIdx.x;
  if (i < n) out[i] = 1.0e6f;
}

// ---------------- fp32 -> bf16 bulk convert (n4 = n/4) ----------------
__global__ __launch_bounds__(256) void k_cvt(const float* __restrict__ s,
                                             u16* __restrict__ d, int n4) {
  int i = blockIdx.x * 256 + threadIdx.x;
  if (i >= n4) return;
  float4 v = reinterpret_cast<const float4*>(s)[i];
  short4 o;
  o.x = (short)f2bf(v.x); o.y = (short)f2bf(v.y);
  o.z = (short)f2bf(v.z); o.w = (short)f2bf(v.w);
  reinterpret_cast<short4*>(d)[i] = o;
}

// ---------------- generic 128x128x32 bf16 GEMM, C = A * B^T ----------------
// MODE 0: out = bf16 [b][h][s][d]            (Q/K projection)
// MODE 1: out = bf16 [bh][d][s], out2 = fp8   (V projection, transposed)
// MODE 2: out = fp32 [m][n] + bias            (output projection)
template <int MODE>
__global__ __launch_bounds__(256, 2) void k_gemm_bt(
    const u16* __restrict__ A, const u16* __restrict__ Bt,
    void* __restrict__ out, void* __restrict__ out2,
    const float* __restrict__ bias, int K, int lda, int ldb, int N) {
  __shared__ __align__(16) u16 lsA[4][128][8];
  __shared__ __align__(16) u16 lsB[4][128][8];
  const int t = threadIdx.x;
  const int mbase = blockIdx.y * 128, nbase = blockIdx.x * 128;
  const int w = t >> 6, l = t & 63;
  const int wr = w >> 1, wc = w & 1;
  const int lr = l & 15, lg = l >> 4;
  f32x4 acc[4][4] = {};
  for (int k0 = 0; k0 < K; k0 += 32) {
#pragma unroll
    for (int i = 0; i < 2; ++i) {
      int idx = t + i * 256;
      int c = idx >> 7, row = idx & 127;
      g2l16(A  + (size_t)(mbase + row) * lda + k0 + c * 8, &lsA[c][row][0]);
      g2l16(Bt + (size_t)(nbase + row) * ldb + k0 + c * 8, &lsB[c][row][0]);
    }
    __syncthreads();
    bf16x8 af[4], bg[4];
#pragma unroll
    for (int f = 0; f < 4; ++f) {
      af[f] = *reinterpret_cast<const bf16x8*>(&lsA[lg][wr * 64 + f * 16 + lr][0]);
      bg[f] = *reinterpret_cast<const bf16x8*>(&lsB[lg][wc * 64 + f * 16 + lr][0]);
    }
#pragma unroll
    for (int mf = 0; mf < 4; ++mf)
#pragma unroll
      for (int nf = 0; nf < 4; ++nf)
        acc[mf][nf] = __builtin_amdgcn_mfma_f32_16x16x32_bf16(af[mf], bg[nf], acc[mf][nf], 0, 0, 0);
    __syncthreads();
  }
#pragma unroll
  for (int mf = 0; mf < 4; ++mf) {
#pragma unroll
    for (int nf = 0; nf < 4; ++nf) {
      const int m0 = mbase + wr * 64 + mf * 16 + lg * 4;
      const int n  = nbase + wc * 64 + nf * 16 + lr;
      if (MODE == 0) {
        int h = n >> 6, d = n & 63;
#pragma unroll
        for (int j = 0; j < 4; ++j) {
          int m = m0 + j, b = m >> 11, s = m & 2047;
          ((u16*)out)[((((size_t)b * NH + h) * SEQ + s) << 6) + d] = f2bf(acc[mf][nf][j]);
        }
      } else if (MODE == 1) {
        int h = n >> 6, d = n & 63;
        int b = m0 >> 11, s0 = m0 & 2047;
        size_t base = (((size_t)b * NH + h) * DH + d) * SEQ + s0;
        short4 pk;
        pk.x = (short)f2bf(acc[mf][nf][0]); pk.y = (short)f2bf(acc[mf][nf][1]);
        pk.z = (short)f2bf(acc[mf][nf][2]); pk.w = (short)f2bf(acc[mf][nf][3]);
        *reinterpret_cast<short4*>(&((u16*)out)[base]) = pk;
        *reinterpret_cast<uint32_t*>(&((u8*)out2)[base]) =
            pk4_fp8(acc[mf][nf][0], acc[mf][nf][1], acc[mf][nf][2], acc[mf][nf][3]);
      } else {
        float bv = bias[n];
#pragma unroll
        for (int j = 0; j < 4; ++j)
          ((float*)out)[(size_t)(m0 + j) * N + n] = acc[mf][nf][j] + bv;
      }
    }
  }
}

// ------- per-head scores: E(fp8) = exp(scale * Q K^T), Dsum += rowsums -------
// Epilogue: fp8 tile bounced through LDS, stored with coalesced dwordx4.
__global__ __launch_bounds__(256, 2) void k_scores(
    const u16* __restrict__ Q, const u16* __restrict__ Kh,
    u8* __restrict__ E, float* __restrict__ Dsum) {
  __shared__ __align__(16) u16 lsA[4][128][8];
  __shared__ __align__(16) u16 lsB[4][128][8];
  __shared__ __align__(16) u8 stile[128 * 144];   // 144-byte row pitch (16B aligned)
  const int t = threadIdx.x;
  const int head = blockIdx.z;
  const int mbase = blockIdx.y * 128, nbase = blockIdx.x * 128;
  const int w = t >> 6, l = t & 63;
  const int wr = w >> 1, wc = w & 1;
  const int lr = l & 15, lg = l >> 4;
  const u16* Aq = Q  + (size_t)head * SEQ * DH;
  const u16* Bk = Kh + (size_t)head * SEQ * DH;
  f32x4 acc[4][4] = {};
  for (int k0 = 0; k0 < DH; k0 += 32) {
#pragma unroll
    for (int i = 0; i < 2; ++i) {
      int idx = t + i * 256;
      int c = idx >> 7, row = idx & 127;
      g2l16(Aq + (size_t)(mbase + row) * DH + k0 + c * 8, &lsA[c][row][0]);
      g2l16(Bk + (size_t)(nbase + row) * DH + k0 + c * 8, &lsB[c][row][0]);
    }
    __syncthreads();
    bf16x8 af[4], bg[4];
#pragma unroll
    for (int f = 0; f < 4; ++f) {
      af[f] = *reinterpret_cast<const bf16x8*>(&lsA[lg][wr * 64 + f * 16 + lr][0]);
      bg[f] = *reinterpret_cast<const bf16x8*>(&lsB[lg][wc * 64 + f * 16 + lr][0]);
    }
#pragma unroll
    for (int mf = 0; mf < 4; ++mf)
#pragma unroll
      for (int nf = 0; nf < 4; ++nf)
        acc[mf][nf] = __builtin_amdgcn_mfma_f32_16x16x32_bf16(af[mf], bg[nf], acc[mf][nf], 0, 0, 0);
    __syncthreads();
  }
  // exp + rowsums + fp8 into LDS tile
  float rs[4][4];
#pragma unroll
  for (int mf = 0; mf < 4; ++mf)
#pragma unroll
    for (int j = 0; j < 4; ++j) rs[mf][j] = 0.f;
#pragma unroll
  for (int mf = 0; mf < 4; ++mf) {
#pragma unroll
    for (int nf = 0; nf < 4; ++nf) {
      const int r0 = wr * 64 + mf * 16 + lg * 4;
      const int c  = wc * 64 + nf * 16 + lr;
#pragma unroll
      for (int j = 0; j < 4; ++j) {
        float e = exp2f(acc[mf][nf][j] * SCALE_LOG2E);
        stile[(r0 + j) * 144 + c] = f2fp8(e);
        rs[mf][j] += e;
      }
    }
  }
#pragma unroll
  for (int mask = 1; mask <= 8; mask <<= 1)
#pragma unroll
    for (int mf = 0; mf < 4; ++mf)
#pragma unroll
      for (int j = 0; j < 4; ++j) rs[mf][j] += __shfl_xor(rs[mf][j], mask, 64);
  if (lr == 0) {
#pragma unroll
    for (int mf = 0; mf < 4; ++mf)
#pragma unroll
      for (int j = 0; j < 4; ++j)
        atomicAdd(&Dsum[head * SEQ + mbase + wr * 64 + mf * 16 + lg * 4 + j], rs[mf][j]);
  }
  __syncthreads();
  // coalesced store: 8 threads cover one 128B row segment
  u8* Eh = E + (size_t)head * SEQ * SEQ;
#pragma unroll
  for (int p = 0; p < 4; ++p) {
    int row = p * 32 + (t >> 3), c16 = t & 7;
    i32x4 v = *reinterpret_cast<const i32x4*>(&stile[row * 144 + c16 * 16]);
    *reinterpret_cast<i32x4*>(&Eh[(size_t)(mbase + row) * SEQ + nbase + c16 * 16]) = v;
  }
}

// ---------------- Fac = beta / Dsum ----------------
__global__ __launch_bounds__(256) void k_fac(const float* __restrict__ Dsum,
                                             float* __restrict__ Fac, int n) {
  int i = blockIdx.x * 256 + threadIdx.x;
  if (i < n) Fac[i] = BETA / Dsum[i];
}

// ------ Horner step (fp8, LDS double-buffered 2-phase): r_out = V + Fac*(E@r) -
// E: [bh][s][s] fp8; rin8/rout8: [bh][d=64][s] fp8; VT: [bh][d][s] bf16.
// Grid: 1024 blocks (64-row M-tiles x 32 heads), 4 blocks/CU.
// LDS granule-major [kc8][row][16]; staging is linear in granule index
// (wave-uniform base + lane*16 satisfied). Stage of chunk c+1 issued BEFORE
// compute of chunk c; single __syncthreads per chunk drains it after MFMAs.
// Head remap: head = (bid%8)*4 + (bid/8)%4 -> each XCD's L2 holds 4 heads' r.
__global__ __launch_bounds__(256, 4) void k_horner8(
    const u8* __restrict__ E, const u8* __restrict__ rin8,
    const u16* __restrict__ VT, const float* __restrict__ Fac,
    u8* __restrict__ rout8, u16* __restrict__ attn, int writeAttn) {
  __shared__ __align__(16) u8 lsA[2][8][64][16];  // 16 KB
  __shared__ __align__(16) u8 lsB[2][8][64][16];  // 16 KB
  const int t = threadIdx.x;
  const int bid = blockIdx.x;
  const int head = ((bid & 7) << 2) | ((bid >> 3) & 3);
  const int mbase = (bid >> 5) * 64;
  const int w = t >> 6, l = t & 63;
  const int lr = l & 15, lg = l >> 4;
  const u8* Eh = E + (size_t)head * SEQ * SEQ + (size_t)mbase * SEQ;
  const u8* Rh = rin8 + (size_t)head * DH * SEQ;
  f32x4 acc[4] = {};
  // stage one 128-byte K-chunk: granule g = i*256+t -> kc8 = g>>6 (= w+4i), row = l
  auto stage = [&](int buf, int k0) {
    g2l16(Eh + (size_t)l * SEQ + k0 + w * 16,        &lsA[buf][w][l][0]);
    g2l16(Eh + (size_t)l * SEQ + k0 + (w + 4) * 16,  &lsA[buf][w + 4][l][0]);
    g2l16(Rh + (size_t)l * SEQ + k0 + w * 16,        &lsB[buf][w][l][0]);
    g2l16(Rh + (size_t)l * SEQ + k0 + (w + 4) * 16,  &lsB[buf][w + 4][l][0]);
  };
  stage(0, 0);
  __syncthreads();
  int cur = 0;
  const int NCH = SEQ / 128;  // 16
  for (int c = 0; c < NCH; ++c) {
    if (c + 1 < NCH) stage(cur ^ 1, (c + 1) * 128);
#pragma unroll
    for (int ks = 0; ks < 4; ++ks) {
      const int gA = 2 * ks + (lg >> 1), bo = (lg & 1) * 8;
      i64 af = *reinterpret_cast<const i64*>(&lsA[cur][gA][w * 16 + lr][bo]);
#pragma unroll
      for (int nf = 0; nf < 4; ++nf) {
        i64 bf = *reinterpret_cast<const i64*>(&lsB[cur][gA][nf * 16 + lr][bo]);
        acc[nf] = __builtin_amdgcn_mfma_f32_16x16x32_fp8_fp8(af, bf, acc[nf], 0, 0, 0);
      }
    }
    __syncthreads();   // drains staged loads (vmcnt) + publishes buf cur^1
    cur ^= 1;
  }
  const u16* VTh = VT + (size_t)head * DH * SEQ;
  const float* Fh = Fac + head * SEQ;
  u8* Ro8 = rout8 + (size_t)head * DH * SEQ;
  const int b = head >> 3, hh = head & 7;
#pragma unroll
  for (int nf = 0; nf < 4; ++nf) {
    const int m0 = mbase + w * 16 + lg * 4;
    const int n  = nf * 16 + lr;
    short4 vv = *reinterpret_cast<const short4*>(&VTh[(size_t)n * SEQ + m0]);
    float4 fc = *reinterpret_cast<const float4*>(&Fh[m0]);
    float o0 = bf2f((u16)vv.x) + fc.x * acc[nf][0];
    float o1 = bf2f((u16)vv.y) + fc.y * acc[nf][1];
    float o2 = bf2f((u16)vv.z) + fc.z * acc[nf][2];
    float o3 = bf2f((u16)vv.w) + fc.w * acc[nf][3];
    *reinterpret_cast<uint32_t*>(&Ro8[(size_t)n * SEQ + m0]) = pk4_fp8(o0, o1, o2, o3);
    if (writeAttn) {
      size_t base = ((size_t)b * SEQ + m0) * DM + hh * DH + n;
      attn[base]          = f2bf(o0);
      attn[base + DM]     = f2bf(o1);
      attn[base + 2 * DM] = f2bf(o2);
      attn[base + 3 * DM] = f2bf(o3);
    }
  }
}

extern "C" void kernel_launch(void* const* d_in, const int* in_sizes, int n_in,
                              void* d_out, int out_size, void* d_ws, size_t ws_size,
                              hipStream_t stream) {
  const float* q_f = (const float*)d_in[0];
  const float* k_f = (const float*)d_in[1];
  const float* v_f = (const float*)d_in[2];
  const float* Wq  = (const float*)d_in[3];
  const float* Wk  = (const float*)d_in[4];
  const float* Wv  = (const float*)d_in[5];
  const float* Wo  = (const float*)d_in[6];
  const float* bo  = (const float*)d_in[7];

  char* ws = (char*)d_ws;
  size_t o = 0;
  auto take = [&](size_t b) { size_t p = o; o += (b + 255) & ~(size_t)255; return p; };
  const size_t SZ_ACT = (size_t)MR * DM * 2;        // 8 MB
  const size_t SZ_W   = (size_t)DM * DM * 2;        // 0.5 MB
  const size_t SZ_R8  = (size_t)BHN * DH * SEQ;     // 4 MB
  size_t o_qbf = take(SZ_ACT);                      // later: attn
  size_t o_kbf = take(SZ_ACT);                      // later: r8A + r8B
  size_t o_vbf = take(SZ_ACT);
  size_t o_wq = take(SZ_W), o_wk = take(SZ_W), o_wv = take(SZ_W), o_wo = take(SZ_W);
  size_t o_Qh = take(SZ_ACT);
  size_t o_Kh = take(SZ_ACT);
  size_t o_VT = take(SZ_ACT);
  size_t o_V8 = take(SZ_R8);
  size_t o_Ds = take((size_t)BHN * SEQ * 4);
  size_t o_Fc = take((size_t)BHN * SEQ * 4);
  size_t o_E  = take((size_t)BHN * SEQ * SEQ);      // 128 MB fp8
  if (ws_size < o) {  // workspace insufficient -> unambiguous diagnostic
    k_diag<<<dim3((out_size + 255) / 256), dim3(256), 0, stream>>>((float*)d_out, out_size);
    return;
  }
  u16* q_bf = (u16*)(ws + o_qbf);
  u16* k_bf = (u16*)(ws + o_kbf);
  u16* v_bf = (u16*)(ws + o_vbf);
  u16* wq_bf = (u16*)(ws + o_wq); u16* wk_bf = (u16*)(ws + o_wk);
  u16* wv_bf = (u16*)(ws + o_wv); u16* wo_bf = (u16*)(ws + o_wo);
  u16* Qh = (u16*)(ws + o_Qh);
  u16* Kh = (u16*)(ws + o_Kh);
  u16* VT = (u16*)(ws + o_VT);
  u8*  V8 = (u8*)(ws + o_V8);
  float* Dsum = (float*)(ws + o_Ds);
  float* Fac  = (float*)(ws + o_Fc);
  u8* E = (u8*)(ws + o_E);
  // aliases (lifetimes disjoint): attn over q_bf, r8 ping-pong over k_bf
  u16* attn = (u16*)(ws + o_qbf);
  u8* r8A = (u8*)(ws + o_kbf);
  u8* r8B = (u8*)(ws + o_kbf + SZ_R8);

  // 1) fp32 -> bf16 conversions
  {
    int n4 = MR * DM / 4;
    k_cvt<<<dim3((n4 + 255) / 256), dim3(256), 0, stream>>>(q_f, q_bf, n4);
    k_cvt<<<dim3((n4 + 255) / 256), dim3(256), 0, stream>>>(k_f, k_bf, n4);
    k_cvt<<<dim3((n4 + 255) / 256), dim3(256), 0, stream>>>(v_f, v_bf, n4);
    int w4 = DM * DM / 4;
    k_cvt<<<dim3((w4 + 255) / 256), dim3(256), 0, stream>>>(Wq, wq_bf, w4);
    k_cvt<<<dim3((w4 + 255) / 256), dim3(256), 0, stream>>>(Wk, wk_bf, w4);
    k_cvt<<<dim3((w4 + 255) / 256), dim3(256), 0, stream>>>(Wv, wv_bf, w4);
    k_cvt<<<dim3((w4 + 255) / 256), dim3(256), 0, stream>>>(Wo, wo_bf, w4);
  }

  // 2) projections
  dim3 pgrid(DM / 128, MR / 128);
  k_gemm_bt<0><<<pgrid, dim3(256), 0, stream>>>(q_bf, wq_bf, Qh, nullptr, nullptr, DM, DM, DM, DM);
  k_gemm_bt<0><<<pgrid, dim3(256), 0, stream>>>(k_bf, wk_bf, Kh, nullptr, nullptr, DM, DM, DM, DM);
  k_gemm_bt<1><<<pgrid, dim3(256), 0, stream>>>(v_bf, wv_bf, VT, V8, nullptr, DM, DM, DM, DM);

  // 3) scores: E = exp(scale*QK^T) in fp8, Dsum = fp32 row sums
  hipMemsetAsync(Dsum, 0, (size_t)BHN * SEQ * 4, stream);
  k_scores<<<dim3(SEQ / 128, SEQ / 128, BHN), dim3(256), 0, stream>>>(Qh, Kh, E, Dsum);
  k_fac<<<dim3(BHN * SEQ / 256), dim3(256), 0, stream>>>(Dsum, Fac, BHN * SEQ);

  // 4) Horner: r <- V + (beta/D) * E @ r, 10 times (r0 = V); last writes attn
  const u8* rin8 = V8;
  u8* r8bufs[2] = {r8A, r8B};
  for (int it = 0; it < NITER; ++it) {
    u8* ro8 = r8bufs[it & 1];
    k_horner8<<<dim3(1024), dim3(256), 0, stream>>>(
        E, rin8, VT, Fac, ro8, attn, (it == NITER - 1) ? 1 : 0);
    rin8 = ro8;
  }

  // 5) output projection: out = attn @ Wo^T + bo (fp32)
  k_gemm_bt<2><<<pgrid, dim3(256), 0, stream>>>(attn, wo_bf, d_out, nullptr, bo, DM, DM, DM, DM);
}

// Round 8
// 547.050 us; speedup vs baseline: 2.1278x; 1.1923x over previous
//
#include <hip/hip_runtime.h>
#include <hip/hip_bf16.h>
#include <stdint.h>

#define SEQ   2048
#define DM    512
#define NH    8
#define DH    64
#define BHN   32        // B*H
#define MR    8192      // B*SEQ
#define NITER 10
#define SCALE_LOG2E 0.18033688011112042f   // (1/8) * log2(e)
#define BETA  0.5f

typedef unsigned short u16;
typedef unsigned char  u8;
typedef long i64;  // 64-bit on amdgcn
typedef __attribute__((ext_vector_type(8))) short bf16x8;
typedef __attribute__((ext_vector_type(4))) float f32x4;
typedef __attribute__((ext_vector_type(4))) int i32x4;

__device__ __forceinline__ u16 f2bf(float f) {
  union { float f; uint32_t u; } v; v.f = f;
  uint32_t r = v.u + 0x7FFFu + ((v.u >> 16) & 1u);
  return (u16)(r >> 16);
}
__device__ __forceinline__ float bf2f(u16 h) {
  union { uint32_t u; float f; } v; v.u = ((uint32_t)h) << 16;
  return v.f;
}
__device__ __forceinline__ void g2l16(const void* g, void* l) {
  __builtin_amdgcn_global_load_lds(
      (const __attribute__((address_space(1))) void*)g,
      (__attribute__((address_space(3))) void*)l, 16, 0, 0);
}
__device__ __forceinline__ uint32_t pk4_fp8(float a, float b, float c, float d) {
  int w = 0;
  w = __builtin_amdgcn_cvt_pk_fp8_f32(a, b, w, false);  // bytes 0,1
  w = __builtin_amdgcn_cvt_pk_fp8_f32(c, d, w, true);   // bytes 2,3
  return (uint32_t)w;
}

// ---------------- diagnostic: fill out with 1e6 (ws too small) ----------------
__global__ __launch_bounds__(256) void k_diag(float* __restrict__ out, int n) {
  int i = blockIdx.x * 256 + threadIdx.x;
  if (i < n) out[i] = 1.0e6f;
}

// ---------------- fp32 -> bf16 bulk convert (n4 = n/4) ----------------
__global__ __launch_bounds__(256) void k_cvt(const float* __restrict__ s,
                                             u16* __restrict__ d, int n4) {
  int i = blockIdx.x * 256 + threadIdx.x;
  if (i >= n4) return;
  float4 v = reinterpret_cast<const float4*>(s)[i];
  short4 o;
  o.x = (short)f2bf(v.x); o.y = (short)f2bf(v.y);
  o.z = (short)f2bf(v.z); o.w = (short)f2bf(v.w);
  reinterpret_cast<short4*>(d)[i] = o;
}

// ---------------- generic 128x128x32 bf16 GEMM, C = A * B^T ----------------
// MODE 0: out = bf16 [b][h][s][d]                     (Q/K projection)
// MODE 1: out = bf16 [bh][d][s], out2 = fp8 r2-layout (V projection)
// MODE 2: out = fp32 [m][n] + bias                    (output projection)
template <int MODE>
__global__ __launch_bounds__(256, 2) void k_gemm_bt(
    const u16* __restrict__ A, const u16* __restrict__ Bt,
    void* __restrict__ out, void* __restrict__ out2,
    const float* __restrict__ bias, int K, int lda, int ldb, int N) {
  __shared__ __align__(16) u16 lsA[4][128][8];
  __shared__ __align__(16) u16 lsB[4][128][8];
  const int t = threadIdx.x;
  const int mbase = blockIdx.y * 128, nbase = blockIdx.x * 128;
  const int w = t >> 6, l = t & 63;
  const int wr = w >> 1, wc = w & 1;
  const int lr = l & 15, lg = l >> 4;
  f32x4 acc[4][4] = {};
  for (int k0 = 0; k0 < K; k0 += 32) {
#pragma unroll
    for (int i = 0; i < 2; ++i) {
      int idx = t + i * 256;
      int c = idx >> 7, row = idx & 127;
      g2l16(A  + (size_t)(mbase + row) * lda + k0 + c * 8, &lsA[c][row][0]);
      g2l16(Bt + (size_t)(nbase + row) * ldb + k0 + c * 8, &lsB[c][row][0]);
    }
    __syncthreads();
    bf16x8 af[4], bg[4];
#pragma unroll
    for (int f = 0; f < 4; ++f) {
      af[f] = *reinterpret_cast<const bf16x8*>(&lsA[lg][wr * 64 + f * 16 + lr][0]);
      bg[f] = *reinterpret_cast<const bf16x8*>(&lsB[lg][wc * 64 + f * 16 + lr][0]);
    }
#pragma unroll
    for (int mf = 0; mf < 4; ++mf)
#pragma unroll
      for (int nf = 0; nf < 4; ++nf)
        acc[mf][nf] = __builtin_amdgcn_mfma_f32_16x16x32_bf16(af[mf], bg[nf], acc[mf][nf], 0, 0, 0);
    __syncthreads();
  }
#pragma unroll
  for (int mf = 0; mf < 4; ++mf) {
#pragma unroll
    for (int nf = 0; nf < 4; ++nf) {
      const int m0 = mbase + wr * 64 + mf * 16 + lg * 4;
      const int n  = nbase + wc * 64 + nf * 16 + lr;
      if (MODE == 0) {
        int h = n >> 6, d = n & 63;
#pragma unroll
        for (int j = 0; j < 4; ++j) {
          int m = m0 + j, b = m >> 11, s = m & 2047;
          ((u16*)out)[((((size_t)b * NH + h) * SEQ + s) << 6) + d] = f2bf(acc[mf][nf][j]);
        }
      } else if (MODE == 1) {
        int h = n >> 6, d = n & 63;
        int b = m0 >> 11, s0 = m0 & 2047;
        short4 pk;
        pk.x = (short)f2bf(acc[mf][nf][0]); pk.y = (short)f2bf(acc[mf][nf][1]);
        pk.z = (short)f2bf(acc[mf][nf][2]); pk.w = (short)f2bf(acc[mf][nf][3]);
        *reinterpret_cast<short4*>(
            &((u16*)out)[(((size_t)b * NH + h) * DH + d) * SEQ + s0]) = pk;
        // fp8 copy in r2 layout: [bh][kc=s/16][d][16]
        size_t v8b = (size_t)(b * NH + h) * (DH * SEQ)
                   + ((size_t)(s0 >> 4) * DH + d) * 16 + (s0 & 15);
        *reinterpret_cast<uint32_t*>(&((u8*)out2)[v8b]) =
            pk4_fp8(acc[mf][nf][0], acc[mf][nf][1], acc[mf][nf][2], acc[mf][nf][3]);
      } else {
        float bv = bias[n];
#pragma unroll
        for (int j = 0; j < 4; ++j)
          ((float*)out)[(size_t)(m0 + j) * N + n] = acc[mf][nf][j] + bv;
      }
    }
  }
}

// ------- scores: E2 = exp(scale*QK^T) in fp8 (k-granule-major layout),
//         Fac = beta / rowsum, computed fully in-block (no atomics).
// Block = 64 q-rows x all 2048 k of one head. Swapped MFMA: mfma(K,Q) makes
// each lane hold 4 CONSECUTIVE k for one q -> dword pack, dense stores.
// E2 layout: [bh][kc=k/16][q][16B]. K staged granule-major LDS, double-buffered.
__global__ __launch_bounds__(256, 4) void k_scores(
    const u16* __restrict__ Q, const u16* __restrict__ Kh,
    u8* __restrict__ E2, float* __restrict__ Fac) {
  __shared__ __align__(16) u16 lsK[2][8][128][8];  // [buf][gran dk/8][kcol][8bf16] = 32 KB
  const int t = threadIdx.x;
  const int b = blockIdx.x;
  const int head = ((b & 7) << 2) | ((b >> 3) & 3);   // XCD-chunked head map
  const int qbase = (b >> 5) * 64;
  const int w = t >> 6, l = t & 63;
  const int lr = l & 15, lg = l >> 4;
  const u16* Qh = Q  + (size_t)head * SEQ * DH;
  const u16* Kp = Kh + (size_t)head * SEQ * DH;
  // Q fragments in registers (B-operand): bg[f] = Q[qbase+w*16+lr][f*32+lg*8 ..+8]
  bf16x8 bg[2];
  bg[0] = *reinterpret_cast<const bf16x8*>(Qh + (size_t)(qbase + w * 16 + lr) * DH + lg * 8);
  bg[1] = *reinterpret_cast<const bf16x8*>(Qh + (size_t)(qbase + w * 16 + lr) * DH + 32 + lg * 8);
  auto stage = [&](int buf, int kb) {
#pragma unroll
    for (int i = 0; i < 4; ++i) {
      int idx = i * 256 + t;
      int g = idx >> 7, kcol = idx & 127;
      g2l16(Kp + (size_t)(kb + kcol) * DH + g * 8, &lsK[buf][g][kcol][0]);
    }
  };
  stage(0, 0);
  __syncthreads();
  float rsum = 0.f;
  int cur = 0;
  u8* Eh = E2 + (size_t)head * SEQ * SEQ;
  const int qrow = qbase + w * 16 + lr;
  for (int tile = 0; tile < 16; ++tile) {
    if (tile + 1 < 16) stage(cur ^ 1, (tile + 1) * 128);
    f32x4 acc[8] = {};
#pragma unroll
    for (int ks = 0; ks < 2; ++ks) {
#pragma unroll
      for (int mf = 0; mf < 8; ++mf) {
        bf16x8 af = *reinterpret_cast<const bf16x8*>(&lsK[cur][ks * 4 + lg][mf * 16 + lr][0]);
        acc[mf] = __builtin_amdgcn_mfma_f32_16x16x32_bf16(af, bg[ks], acc[mf], 0, 0, 0);
      }
    }
#pragma unroll
    for (int mf = 0; mf < 8; ++mf) {
      float e0 = exp2f(acc[mf][0] * SCALE_LOG2E);
      float e1 = exp2f(acc[mf][1] * SCALE_LOG2E);
      float e2 = exp2f(acc[mf][2] * SCALE_LOG2E);
      float e3 = exp2f(acc[mf][3] * SCALE_LOG2E);
      rsum += (e0 + e1) + (e2 + e3);
      *reinterpret_cast<uint32_t*>(
          &Eh[((size_t)(tile * 8 + mf) * SEQ + qrow) * 16 + lg * 4]) =
          pk4_fp8(e0, e1, e2, e3);
    }
    __syncthreads();
    cur ^= 1;
  }
  rsum += __shfl_xor(rsum, 16, 64);
  rsum += __shfl_xor(rsum, 32, 64);
  if (lg == 0) Fac[head * SEQ + qrow] = BETA / rsum;
}

// ------ Horner step (fp8, LDS dbuf 2-phase, granule-major global layouts) ----
// E2: [bh][kc][q][16] fp8; r2 in/out: [bh][kc][d][16] fp8; VT: [bh][d][s] bf16.
// Staging is lane-contiguous 1KB wave transactions (no L2 amplification).
// LDS layout and fragment indexing identical to verified round-5 kernel.
__global__ __launch_bounds__(256, 4) void k_horner8(
    const u8* __restrict__ E2, const u8* __restrict__ rin2,
    const u16* __restrict__ VT, const float* __restrict__ Fac,
    u8* __restrict__ rout2, u16* __restrict__ attn, int writeAttn) {
  __shared__ __align__(16) u8 lsA[2][8][64][16];  // 16 KB
  __shared__ __align__(16) u8 lsB[2][8][64][16];  // 16 KB
  const int t = threadIdx.x;
  const int bid = blockIdx.x;
  const int head = ((bid & 7) << 2) | ((bid >> 3) & 3);
  const int mbase = (bid >> 5) * 64;
  const int w = t >> 6, l = t & 63;
  const int lr = l & 15, lg = l >> 4;
  const u8* Eh = E2 + (size_t)head * SEQ * SEQ;      // per head: 128 kc x 2048 q x 16
  const u8* Rh = rin2 + (size_t)head * DH * SEQ;     // per head: 128 kc x 64 d x 16
  f32x4 acc[4] = {};
  auto stage = [&](int buf, int c) {
    const int c8 = c * 8;
    g2l16(Eh + ((size_t)(c8 + w)     * SEQ + mbase + l) * 16, &lsA[buf][w][l][0]);
    g2l16(Eh + ((size_t)(c8 + w + 4) * SEQ + mbase + l) * 16, &lsA[buf][w + 4][l][0]);
    g2l16(Rh + ((size_t)(c8 + w)     * DH + l) * 16,          &lsB[buf][w][l][0]);
    g2l16(Rh + ((size_t)(c8 + w + 4) * DH + l) * 16,          &lsB[buf][w + 4][l][0]);
  };
  stage(0, 0);
  __syncthreads();
  int cur = 0;
  const int NCH = SEQ / 128;  // 16
  for (int c = 0; c < NCH; ++c) {
    if (c + 1 < NCH) stage(cur ^ 1, c + 1);
#pragma unroll
    for (int ks = 0; ks < 4; ++ks) {
      const int gA = 2 * ks + (lg >> 1), bo = (lg & 1) * 8;
      i64 af = *reinterpret_cast<const i64*>(&lsA[cur][gA][w * 16 + lr][bo]);
#pragma unroll
      for (int nf = 0; nf < 4; ++nf) {
        i64 bf = *reinterpret_cast<const i64*>(&lsB[cur][gA][nf * 16 + lr][bo]);
        acc[nf] = __builtin_amdgcn_mfma_f32_16x16x32_fp8_fp8(af, bf, acc[nf], 0, 0, 0);
      }
    }
    __syncthreads();
    cur ^= 1;
  }
  const u16* VTh = VT + (size_t)head * DH * SEQ;
  const float* Fh = Fac + head * SEQ;
  u8* Ro = rout2 + (size_t)head * DH * SEQ;
  const int b = head >> 3, hh = head & 7;
#pragma unroll
  for (int nf = 0; nf < 4; ++nf) {
    const int m0 = mbase + w * 16 + lg * 4;
    const int n  = nf * 16 + lr;
    short4 vv = *reinterpret_cast<const short4*>(&VTh[(size_t)n * SEQ + m0]);
    float4 fc = *reinterpret_cast<const float4*>(&Fh[m0]);
    float o0 = bf2f((u16)vv.x) + fc.x * acc[nf][0];
    float o1 = bf2f((u16)vv.y) + fc.y * acc[nf][1];
    float o2 = bf2f((u16)vv.z) + fc.z * acc[nf][2];
    float o3 = bf2f((u16)vv.w) + fc.w * acc[nf][3];
    *reinterpret_cast<uint32_t*>(
        &Ro[((size_t)(m0 >> 4) * DH + n) * 16 + (m0 & 15)]) = pk4_fp8(o0, o1, o2, o3);
    if (writeAttn) {
      size_t base = ((size_t)b * SEQ + m0) * DM + hh * DH + n;
      attn[base]          = f2bf(o0);
      attn[base + DM]     = f2bf(o1);
      attn[base + 2 * DM] = f2bf(o2);
      attn[base + 3 * DM] = f2bf(o3);
    }
  }
}

extern "C" void kernel_launch(void* const* d_in, const int* in_sizes, int n_in,
                              void* d_out, int out_size, void* d_ws, size_t ws_size,
                              hipStream_t stream) {
  const float* q_f = (const float*)d_in[0];
  const float* k_f = (const float*)d_in[1];
  const float* v_f = (const float*)d_in[2];
  const float* Wq  = (const float*)d_in[3];
  const float* Wk  = (const float*)d_in[4];
  const float* Wv  = (const float*)d_in[5];
  const float* Wo  = (const float*)d_in[6];
  const float* bo  = (const float*)d_in[7];

  char* ws = (char*)d_ws;
  size_t o = 0;
  auto take = [&](size_t b) { size_t p = o; o += (b + 255) & ~(size_t)255; return p; };
  const size_t SZ_ACT = (size_t)MR * DM * 2;        // 8 MB
  const size_t SZ_W   = (size_t)DM * DM * 2;        // 0.5 MB
  const size_t SZ_R8  = (size_t)BHN * DH * SEQ;     // 4 MB
  size_t o_qbf = take(SZ_ACT);                      // later: attn
  size_t o_kbf = take(SZ_ACT);                      // later: r8A + r8B
  size_t o_vbf = take(SZ_ACT);
  size_t o_wq = take(SZ_W), o_wk = take(SZ_W), o_wv = take(SZ_W), o_wo = take(SZ_W);
  size_t o_Qh = take(SZ_ACT);
  size_t o_Kh = take(SZ_ACT);
  size_t o_VT = take(SZ_ACT);
  size_t o_V8 = take(SZ_R8);
  size_t o_Fc = take((size_t)BHN * SEQ * 4);
  size_t o_E  = take((size_t)BHN * SEQ * SEQ);      // 128 MB fp8
  if (ws_size < o) {  // workspace insufficient -> unambiguous diagnostic
    k_diag<<<dim3((out_size + 255) / 256), dim3(256), 0, stream>>>((float*)d_out, out_size);
    return;
  }
  u16* q_bf = (u16*)(ws + o_qbf);
  u16* k_bf = (u16*)(ws + o_kbf);
  u16* v_bf = (u16*)(ws + o_vbf);
  u16* wq_bf = (u16*)(ws + o_wq); u16* wk_bf = (u16*)(ws + o_wk);
  u16* wv_bf = (u16*)(ws + o_wv); u16* wo_bf = (u16*)(ws + o_wo);
  u16* Qh = (u16*)(ws + o_Qh);
  u16* Kh = (u16*)(ws + o_Kh);
  u16* VT = (u16*)(ws + o_VT);
  u8*  V8 = (u8*)(ws + o_V8);
  float* Fac  = (float*)(ws + o_Fc);
  u8* E = (u8*)(ws + o_E);
  // aliases (lifetimes disjoint): attn over q_bf, r2 ping-pong over k_bf
  u16* attn = (u16*)(ws + o_qbf);
  u8* r8A = (u8*)(ws + o_kbf);
  u8* r8B = (u8*)(ws + o_kbf + SZ_R8);

  // 1) fp32 -> bf16 conversions
  {
    int n4 = MR * DM / 4;
    k_cvt<<<dim3((n4 + 255) / 256), dim3(256), 0, stream>>>(q_f, q_bf, n4);
    k_cvt<<<dim3((n4 + 255) / 256), dim3(256), 0, stream>>>(k_f, k_bf, n4);
    k_cvt<<<dim3((n4 + 255) / 256), dim3(256), 0, stream>>>(v_f, v_bf, n4);
    int w4 = DM * DM / 4;
    k_cvt<<<dim3((w4 + 255) / 256), dim3(256), 0, stream>>>(Wq, wq_bf, w4);
    k_cvt<<<dim3((w4 + 255) / 256), dim3(256), 0, stream>>>(Wk, wk_bf, w4);
    k_cvt<<<dim3((w4 + 255) / 256), dim3(256), 0, stream>>>(Wv, wv_bf, w4);
    k_cvt<<<dim3((w4 + 255) / 256), dim3(256), 0, stream>>>(Wo, wo_bf, w4);
  }

  // 2) projections
  dim3 pgrid(DM / 128, MR / 128);
  k_gemm_bt<0><<<pgrid, dim3(256), 0, stream>>>(q_bf, wq_bf, Qh, nullptr, nullptr, DM, DM, DM, DM);
  k_gemm_bt<0><<<pgrid, dim3(256), 0, stream>>>(k_bf, wk_bf, Kh, nullptr, nullptr, DM, DM, DM, DM);
  k_gemm_bt<1><<<pgrid, dim3(256), 0, stream>>>(v_bf, wv_bf, VT, V8, nullptr, DM, DM, DM, DM);

  // 3) scores: E2 = exp(scale*QK^T) fp8 (granule-major), Fac = beta/rowsum
  k_scores<<<dim3(1024), dim3(256), 0, stream>>>(Qh, Kh, E, Fac);

  // 4) Horner: r <- V + (beta/D) * E @ r, 10 times (r0 = V); last writes attn
  const u8* rin = V8;
  u8* rbufs[2] = {r8A, r8B};
  for (int it = 0; it < NITER; ++it) {
    u8* ro = rbufs[it & 1];
    k_horner8<<<dim3(1024), dim3(256), 0, stream>>>(
        E, rin, VT, Fac, ro, attn, (it == NITER - 1) ? 1 : 0);
    rin = ro;
  }

  // 5) output projection: out = attn @ Wo^T + bo (fp32)
  k_gemm_bt<2><<<pgrid, dim3(256), 0, stream>>>(attn, wo_bf, d_out, nullptr, bo, DM, DM, DM, DM);
}